// Round 16
// baseline (132.521 us; speedup 1.0000x reference)
//
#include <hip/hip_runtime.h>

// KMeans soft-assignment via bf16 hi/lo split MFMA (3 passes), fused softmax.
// logits = (2*x.c - ||c||^2)/T, T=0.1; ||x||^2 cancels in softmax.
// R26: TWO CO-RESIDENT HALF-BLOCKS. R25 (hybrid @1blk/CU) was -2.7us: g1
// direct-B loads were youngest in vmcnt queue -> their wait force-drained
// the fresh DMA. But it proved half-staging fits 68KB LDS. New fact: tail
// is ~12-16us WRITE-BOUND (64MB out) and grid=256=1blk/CU overlaps nothing.
// R26 = R11 geometry (BM=64, 8 waves 2wm x 4wn, acc[2][8]=64 AGPR, arch
// VGPR measured 64 -> fits 128-cap, 4 waves/SIMD) + R20 schedule (1
// barrier/chunk, counted vmcnt(4), DMA-after-barrier) + half-staging with
// the QUEUE FIX: g1 direct loads issue right after the barrier BEFORE
// DMA(ks+1) -> their compiler wait is counted (DMA younger, stays in
// flight; only already-arrived A drains). grid=512 -> 2 independent
// blocks/CU: separate barrier groups break the 8-wave convoy; the two
// blocks' write-bound tails interleave. Per-acc pass order h*h,h*l,l*h
// and chunk order unchanged -> bit-identical (absmax 0.00390625).
// x: [32768,256] f32, c: [512,256] f32, out: [32768,512] f32
#define NROWS 32768
#define KC 512
#define DDIM 256
#define BM 64
#define BK 32
#define KCH (DDIM / BK)        // 8 k-chunks
#define CHUNK_USH (KC * BK)    // 16384 ushorts = 32 KB per chunk table
#define HALF_USH 8192          // staged half-table: 16 tiles (tt<4 of each wn)

typedef __attribute__((ext_vector_type(8))) short bf16x8;
typedef __attribute__((ext_vector_type(4))) float f32x4;

union U8 { unsigned short u[8]; bf16x8 v; };

__device__ __forceinline__ unsigned short f2bf(float f) {   // RNE f32->bf16
    union { float f; unsigned int u; } a; a.f = f;
    unsigned int r = a.u + 0x7fffu + ((a.u >> 16) & 1u);
    return (unsigned short)(r >> 16);
}
__device__ __forceinline__ float bf2f(unsigned short h) {
    union { unsigned int u; float f; } a; a.u = ((unsigned int)h) << 16;
    return a.f;
}
// async global->LDS, 16B/lane; LDS dst must be wave-uniform base + lane*16
__device__ __forceinline__ void ld16(const void* g, void* l) {
    __builtin_amdgcn_global_load_lds(
        (const __attribute__((address_space(1))) unsigned int*)g,
        (__attribute__((address_space(3))) unsigned int*)l, 16, 0, 0);
}

// ---- prep: c -> chunk-major, swizzle-baked bf16 hi/lo + csq10 ----
// octet (col n, quad q) at chunk offset (n*4 + (q ^ ((n>>1)&3)))*8 ushorts.
// Each 16-col tile T is a contiguous 512-ushort (1KB) blob within the chunk.
__global__ __launch_bounds__(64) void prep_c(const float* __restrict__ c,
                                             unsigned short* __restrict__ bhi,
                                             unsigned short* __restrict__ blo,
                                             float* __restrict__ csq10) {
    const int n = blockIdx.x, lane = threadIdx.x;
    const int d0 = lane * 4;
    float4 v = ((const float4*)(c + (size_t)n * DDIM))[lane];
    float vv[4] = {v.x, v.y, v.z, v.w};
    unsigned short hh[4], ll[4];
    float ssq = 0.f;
    #pragma unroll
    for (int i = 0; i < 4; ++i) {
        ssq += vv[i] * vv[i];
        hh[i] = f2bf(vv[i]);
        ll[i] = f2bf(vv[i] - bf2f(hh[i]));
    }
    #pragma unroll
    for (int off = 32; off; off >>= 1) ssq += __shfl_xor(ssq, off);
    if (lane == 0) csq10[n] = 10.f * ssq;
    const int ks = d0 >> 5;
    const int q  = (d0 >> 3) & 3;
    const int s  = q ^ ((n >> 1) & 3);
    const size_t dst = (size_t)ks * CHUNK_USH + (n * 4 + s) * 8 + (d0 & 7);
    *(ushort4*)(bhi + dst) = make_ushort4(hh[0], hh[1], hh[2], hh[3]);
    *(ushort4*)(blo + dst) = make_ushort4(ll[0], ll[1], ll[2], ll[3]);
}

// ---- main: 512 blocks x 512 threads (8 waves = 2 M-groups x 4 N-quarters) ----
union SmemU {
    struct { unsigned short Bh[2][HALF_USH], Bl[2][HALF_USH]; } k;  // 64 KB
    float lbuf[16 * 516];                                           // 33 KB overlay
};

__global__ __launch_bounds__(512, 4) void kmeans_mfma(
    const float* __restrict__ x, const unsigned short* __restrict__ bhi,
    const unsigned short* __restrict__ blo, const float* __restrict__ csq10,
    float* __restrict__ out) {
    __shared__ __align__(16) SmemU sm;
    __shared__ float red[2][4][BM];   // 2 KB

    const int tid  = threadIdx.x;
    const int w    = tid >> 6, lane = tid & 63;
    const int wm   = w >> 2, wn = w & 3;
    const int cc   = lane & 15, q = lane >> 4;
    const int row0 = blockIdx.x * BM;

    f32x4 acc[2][8];
    #pragma unroll
    for (int mt = 0; mt < 2; ++mt)
        #pragma unroll
        for (int t = 0; t < 8; ++t) acc[mt][t] = (f32x4){0.f, 0.f, 0.f, 0.f};

    // A: lane owns rows (row0 + wm*32 + mt*16 + cc), k-octet q*8 per chunk
    const float* xA0 = x + (size_t)(row0 + wm * 32 + cc) * DDIM + q * 8;
    const float* xA1 = xA0 + (size_t)16 * DDIM;
    // per-lane fragment offset within a 1KB tile blob (swizzle baked by prep)
    const int sF = q ^ ((cc >> 1) & 3);
    const int bF = (4 * cc + sF) * 8;
    // staged tiles: s in [0,16) -> global tile T(s) = (s>>2)*8 + (s&3)
    // (tiles with (T&7)<4). DMA: wave w stages s = {2w, 2w+1}.
    const int s0 = w * 2;
    const int T0 = (s0 >> 2) * 8 + (s0 & 3);   // s0 even -> T0, T0+1 pair

    // ---- prologue: issue A(0); DMA half-table chunk 0 -> buf 0 ----
    float4 c00 = *(const float4*)xA0;
    float4 c01 = *(const float4*)(xA0 + 4);
    float4 c10 = *(const float4*)xA1;
    float4 c11 = *(const float4*)(xA1 + 4);
    ld16(bhi + (size_t)T0 * 512 + lane * 8,       &sm.k.Bh[0][s0 * 512]);
    ld16(bhi + (size_t)(T0 + 1) * 512 + lane * 8, &sm.k.Bh[0][(s0 + 1) * 512]);
    ld16(blo + (size_t)T0 * 512 + lane * 8,       &sm.k.Bl[0][s0 * 512]);
    ld16(blo + (size_t)(T0 + 1) * 512 + lane * 8, &sm.k.Bl[0][(s0 + 1) * 512]);

    for (int ks = 0; ks < KCH; ++ks) {
        const int pp = ks & 1;
        // convert A(ks): compiler-counted wait (DMA(ks)'s 4 ops younger)
        bf16x8 ah[2], al[2];
        {
            float v0[8] = {c00.x, c00.y, c00.z, c00.w, c01.x, c01.y, c01.z, c01.w};
            float v1[8] = {c10.x, c10.y, c10.z, c10.w, c11.x, c11.y, c11.z, c11.w};
            U8 H0, L0, H1, L1;
            #pragma unroll
            for (int e = 0; e < 8; ++e) {
                H0.u[e] = f2bf(v0[e]); L0.u[e] = f2bf(v0[e] - bf2f(H0.u[e]));
                H1.u[e] = f2bf(v1[e]); L1.u[e] = f2bf(v1[e] - bf2f(H1.u[e]));
            }
            ah[0] = H0.v; al[0] = L0.v; ah[1] = H1.v; al[1] = L1.v;
        }
        // issue A(ks+1) raw (youngest; in flight across the barrier)
        float4 n00, n01, n10, n11;
        if (ks < KCH - 1) {
            const int kn = (ks + 1) * BK;
            n00 = *(const float4*)(xA0 + kn);
            n01 = *(const float4*)(xA0 + kn + 4);
            n10 = *(const float4*)(xA1 + kn);
            n11 = *(const float4*)(xA1 + kn + 4);
        }
        __builtin_amdgcn_sched_barrier(0);
        // counted wait: DMA(ks) (4 oldest) done; A(ks+1) stays in flight
        if (ks < KCH - 1) {
            asm volatile("s_waitcnt vmcnt(4)" ::: "memory");
        } else {
            asm volatile("s_waitcnt vmcnt(0)" ::: "memory");
        }
        __builtin_amdgcn_s_barrier();
        __builtin_amdgcn_sched_barrier(0);

        // g1 DIRECT phase first (queue fix): these loads are issued BEFORE
        // DMA(ks+1), so their compiler wait leaves the DMA in flight and
        // drains only A(ks+1) (already arrived). 2 subs x {4 loads, 12 MFMA}.
        const size_t go = (size_t)ks * CHUNK_USH + bF;
        #pragma unroll
        for (int sub = 0; sub < 2; ++sub) {
            bf16x8 bh[2], bl[2];
            #pragma unroll
            for (int tt = 0; tt < 2; ++tt) {
                const int T = wn * 8 + 4 + sub * 2 + tt;
                bh[tt] = *(const bf16x8*)(bhi + go + T * 512);
                bl[tt] = *(const bf16x8*)(blo + go + T * 512);
            }
            #pragma unroll
            for (int tt = 0; tt < 2; ++tt) {
                const int t = 4 + sub * 2 + tt;
                acc[0][t] = __builtin_amdgcn_mfma_f32_16x16x32_bf16(ah[0], bh[tt], acc[0][t], 0, 0, 0);
                acc[1][t] = __builtin_amdgcn_mfma_f32_16x16x32_bf16(ah[1], bh[tt], acc[1][t], 0, 0, 0);
            }
            #pragma unroll
            for (int tt = 0; tt < 2; ++tt) {
                const int t = 4 + sub * 2 + tt;
                acc[0][t] = __builtin_amdgcn_mfma_f32_16x16x32_bf16(ah[0], bl[tt], acc[0][t], 0, 0, 0);
                acc[1][t] = __builtin_amdgcn_mfma_f32_16x16x32_bf16(ah[1], bl[tt], acc[1][t], 0, 0, 0);
            }
            #pragma unroll
            for (int tt = 0; tt < 2; ++tt) {
                const int t = 4 + sub * 2 + tt;
                acc[0][t] = __builtin_amdgcn_mfma_f32_16x16x32_bf16(al[0], bh[tt], acc[0][t], 0, 0, 0);
                acc[1][t] = __builtin_amdgcn_mfma_f32_16x16x32_bf16(al[1], bh[tt], acc[1][t], 0, 0, 0);
            }
        }

        // issue DMA(ks+1) half-table -> other slot (post-barrier safe; covered
        // by g0 phase + next chunk's convert before its vmcnt(4))
        if (ks < KCH - 1) {
            const size_t cb = (size_t)(ks + 1) * CHUNK_USH;
            ld16(bhi + cb + T0 * 512 + lane * 8,       &sm.k.Bh[1 - pp][s0 * 512]);
            ld16(bhi + cb + (T0 + 1) * 512 + lane * 8, &sm.k.Bh[1 - pp][(s0 + 1) * 512]);
            ld16(blo + cb + T0 * 512 + lane * 8,       &sm.k.Bl[1 - pp][s0 * 512]);
            ld16(blo + cb + (T0 + 1) * 512 + lane * 8, &sm.k.Bl[1 - pp][(s0 + 1) * 512]);
        }

        // g0 STAGED phase from buf pp: 2 subs x {4 ds_read, 12 MFMA}
        #pragma unroll
        for (int sub = 0; sub < 2; ++sub) {
            bf16x8 bh[2], bl[2];
            #pragma unroll
            for (int tt = 0; tt < 2; ++tt) {
                const int so = (wn * 4 + sub * 2 + tt) * 512 + bF;
                bh[tt] = *(const bf16x8*)&sm.k.Bh[pp][so];
                bl[tt] = *(const bf16x8*)&sm.k.Bl[pp][so];
            }
            #pragma unroll
            for (int tt = 0; tt < 2; ++tt) {
                const int t = sub * 2 + tt;
                acc[0][t] = __builtin_amdgcn_mfma_f32_16x16x32_bf16(ah[0], bh[tt], acc[0][t], 0, 0, 0);
                acc[1][t] = __builtin_amdgcn_mfma_f32_16x16x32_bf16(ah[1], bh[tt], acc[1][t], 0, 0, 0);
            }
            #pragma unroll
            for (int tt = 0; tt < 2; ++tt) {
                const int t = sub * 2 + tt;
                acc[0][t] = __builtin_amdgcn_mfma_f32_16x16x32_bf16(ah[0], bl[tt], acc[0][t], 0, 0, 0);
                acc[1][t] = __builtin_amdgcn_mfma_f32_16x16x32_bf16(ah[1], bl[tt], acc[1][t], 0, 0, 0);
            }
            #pragma unroll
            for (int tt = 0; tt < 2; ++tt) {
                const int t = sub * 2 + tt;
                acc[0][t] = __builtin_amdgcn_mfma_f32_16x16x32_bf16(al[0], bh[tt], acc[0][t], 0, 0, 0);
                acc[1][t] = __builtin_amdgcn_mfma_f32_16x16x32_bf16(al[1], bh[tt], acc[1][t], 0, 0, 0);
            }
        }
        c00 = n00; c01 = n01; c10 = n10; c11 = n11;
    }

    // ---- softmax stats: reduce over t, then cc-lanes, then 4 wn groups ----
    float csqv[8];
    #pragma unroll
    for (int t = 0; t < 8; ++t) csqv[t] = csq10[wn * 128 + t * 16 + cc];
    const int rb = wm * 32 + q * 4;   // + mt*16 + g
    float M[2][4], I[2][4];
    #pragma unroll
    for (int mt = 0; mt < 2; ++mt)
        #pragma unroll
        for (int g = 0; g < 4; ++g) {
            float pm = -1e30f;
            #pragma unroll
            for (int t = 0; t < 8; ++t) pm = fmaxf(pm, 20.f * acc[mt][t][g] - csqv[t]);
            #pragma unroll
            for (int off = 1; off < 16; off <<= 1) pm = fmaxf(pm, __shfl_xor(pm, off));
            if (cc == 0) red[0][wn][rb + mt * 16 + g] = pm;
        }
    __syncthreads();
    #pragma unroll
    for (int mt = 0; mt < 2; ++mt)
        #pragma unroll
        for (int g = 0; g < 4; ++g) {
            const int ri = rb + mt * 16 + g;
            const float m = fmaxf(fmaxf(red[0][0][ri], red[0][1][ri]),
                                  fmaxf(red[0][2][ri], red[0][3][ri]));
            M[mt][g] = m;
            float ps = 0.f;
            #pragma unroll
            for (int t = 0; t < 8; ++t) ps += __expf(20.f * acc[mt][t][g] - csqv[t] - m);
            #pragma unroll
            for (int off = 1; off < 16; off <<= 1) ps += __shfl_xor(ps, off);
            if (cc == 0) red[1][wn][ri] = ps;
        }
    __syncthreads();
    #pragma unroll
    for (int mt = 0; mt < 2; ++mt)
        #pragma unroll
        for (int g = 0; g < 4; ++g) {
            const int ri = rb + mt * 16 + g;
            I[mt][g] = 1.f / (red[1][0][ri] + red[1][1][ri] +
                              red[1][2][ri] + red[1][3][ri]);
        }

    // ---- transpose epilogue: 4 passes of 16 rows through lbuf (R11's) ----
    #pragma unroll
    for (int p = 0; p < 4; ++p) {
        if (wm == (p >> 1)) {
            const int mt = p & 1;
            #pragma unroll
            for (int g = 0; g < 4; ++g) {
                const int   lr = q * 4 + g;
                const float mg = M[mt][g], ig = I[mt][g];
                #pragma unroll
                for (int t = 0; t < 8; ++t)
                    sm.lbuf[lr * 516 + wn * 128 + t * 16 + cc] =
                        __expf(20.f * acc[mt][t][g] - csqv[t] - mg) * ig;
            }
        }
        __syncthreads();
        #pragma unroll
        for (int j = 0; j < 4; ++j) {
            const int f    = j * 512 + tid;     // 0..2047 float4 slots
            const int lrow = f >> 7;            // 0..15
            const int c4   = f & 127;
            float4    v    = *(const float4*)&sm.lbuf[lrow * 516 + c4 * 4];
            *(float4*)(out + (size_t)(row0 + p * 16 + lrow) * KC + c4 * 4) = v;
        }
        __syncthreads();
    }
}

extern "C" void kernel_launch(void* const* d_in, const int* in_sizes, int n_in,
                              void* d_out, int out_size, void* d_ws, size_t ws_size,
                              hipStream_t stream) {
    const float* x   = (const float*)d_in[0];
    const float* c   = (const float*)d_in[1];
    float*       out = (float*)d_out;

    unsigned short* bhi   = (unsigned short*)d_ws;                 // 256 KB
    unsigned short* blo   = bhi + (size_t)KCH * CHUNK_USH;         // 256 KB
    float*          csq10 = (float*)(blo + (size_t)KCH * CHUNK_USH);  // 2 KB

    prep_c<<<KC, 64, 0, stream>>>(c, bhi, blo, csq10);
    kmeans_mfma<<<NROWS / BM, 512, 0, stream>>>(x, bhi, blo, csq10, out);
}